// Round 13
// baseline (191.251 us; speedup 1.0000x reference)
//
#include <hip/hip_runtime.h>
#include <hip/hip_cooperative_groups.h>

#define NI 8
#define NF 100
#define NH 40
#define NC 40
#define NM 41
#define BSZ 2048
#define BT 64
#define XPAD 104   // x-tile LDS row stride (floats), zero-padded 100..103
#define MSTR 68    // msxT row stride (floats)

typedef __attribute__((ext_vector_type(8))) short bf16x8;
typedef __attribute__((ext_vector_type(4))) float f32x4;
typedef __attribute__((ext_vector_type(4))) unsigned int u32x4;

__device__ __forceinline__ unsigned short f2bf(float f) {
    unsigned int u = __builtin_bit_cast(unsigned int, f);
    u += 0x7fffu + ((u >> 16) & 1u);
    return (unsigned short)(u >> 16);
}
__device__ __forceinline__ float bf2f(unsigned short s) {
    unsigned int u = ((unsigned int)s) << 16;
    return __builtin_bit_cast(float, u);
}
__device__ __forceinline__ bf16x8 pack8(float4 u, float4 v) {
    u32x4 w;
    w.x = (unsigned int)f2bf(u.x) | ((unsigned int)f2bf(u.y) << 16);
    w.y = (unsigned int)f2bf(u.z) | ((unsigned int)f2bf(u.w) << 16);
    w.z = (unsigned int)f2bf(v.x) | ((unsigned int)f2bf(v.y) << 16);
    w.w = (unsigned int)f2bf(v.z) | ((unsigned int)f2bf(v.w) << 16);
    return __builtin_bit_cast(bf16x8, w);
}

// ---------------------------------------------------------------------------
// Merged cooperative kernel = W-build (R12's build_w, distributed over the
// grid, overlapped with x/mask staging) + grid.sync + R10's fused body
// (verified best: depth-1 in-place B-frag reload, (512,1), no spills).
// Grid MUST be 256 blocks (1/CU, LDS-limited) and launched cooperatively.
//   Wb1: [ic][nt(3)][k(4)][lane(64)] x16B; n=nt*16+(lane&15), f=k*32+(lane>>4)*8+j
//   Wb2: [ic][nt(7)][kk(2)][lane(64)] x16B; n=nt*16+(lane&15), h=kk*32+(lane>>4)*8+j
// ---------------------------------------------------------------------------
__global__ __launch_bounds__(512, 1) void merged_kernel(
    const float* __restrict__ x, const float* __restrict__ mask,
    const float* __restrict__ A, const float* __restrict__ Bp,
    const float* __restrict__ b_final,
    unsigned short* __restrict__ Wb1, unsigned short* __restrict__ Wb2,
    float* __restrict__ out)
{
    __shared__ __align__(16) float msxT[NC * MSTR];          // 10880 B, [c][b]
    __shared__ __align__(16) unsigned char regionB[71680];   // unions:
    // pre-sync : xs[0,26624) | As[26624,43024) | Bs[43024,49584) | Ws[49584,65584)
    // pass1 out: hsP[g(8)][b(64)][h(48)] bf16 [0,49152)
    // pass2 out: outP[cp(4)][b(64)][f(112)] bf16 [0,57344)
    unsigned short* region = (unsigned short*)regionB;
    float* xs = (float*)regionB;
    float* As = (float*)(regionB + 26624);
    float* Bs = (float*)(regionB + 43024);
    float* Ws = (float*)(regionB + 49584);

    const int tid  = threadIdx.x;
    const int lane = tid & 63;
    const int wav  = tid >> 6;       // 0..7
    const int col  = lane & 15;
    const int quad = lane >> 4;
    const int i    = blockIdx.x % NI;
    const int b0   = (blockIdx.x / NI) * BT;

    // ---- stage mask (fp32, transposed) + x tile (coalesced float4) ----
    for (int idx = tid; idx < BT * NC; idx += 512) {
        const int b = idx / NC, c = idx % NC;     // coalesced global read
        msxT[c * MSTR + b] = mask[((size_t)(b0 + b) * NI + i) * NC + c];
    }
    for (int idx = tid; idx < BT * (XPAD / 4); idx += 512) {
        const int row = idx / (XPAD / 4), fq = idx % (XPAD / 4);
        float4 v = make_float4(0.f, 0.f, 0.f, 0.f);
        if (fq < NF / 4)
            v = *(const float4*)(x + ((size_t)(b0 + row) * NI + i) * NF + fq * 4);
        *(float4*)&xs[row * XPAD + fq * 4] = v;
    }

    // ---- W-build: this block's unit(s). 320 units / 256 blocks: blk<64 do 2 ----
    const int nu = (blockIdx.x < 64) ? 2 : 1;
    for (int t = 0; t < nu; ++t) {
        const int ic = blockIdx.x + t * 256;
        const float* Ap  = A  + (size_t)ic * NF * NM;
        const float* Bpp = Bp + (size_t)ic * NM * NH;
        for (int idx = tid; idx < NF * NM; idx += 512) As[idx] = Ap[idx];
        for (int idx = tid; idx < NM * NH; idx += 512) Bs[idx] = Bpp[idx];
        __syncthreads();
        for (int idx = tid; idx < NF * (NH / 4); idx += 512) {
            const int f  = idx / (NH / 4);
            const int hq = idx % (NH / 4);
            float4 acc = make_float4(0.f, 0.f, 0.f, 0.f);
            #pragma unroll
            for (int m = 0; m < NM; ++m) {
                const float  a = As[f * NM + m];
                const float4 b = *(const float4*)&Bs[m * NH + hq * 4];
                acc.x += a * b.x; acc.y += a * b.y; acc.z += a * b.z; acc.w += a * b.w;
            }
            *(float4*)&Ws[f * NH + hq * 4] = acc;
        }
        __syncthreads();
        for (int e = tid; e < 768; e += 512) {
            const int nt = e >> 8, k = (e >> 6) & 3, ln = e & 63;
            const int colx = ln & 15, qd = ln >> 4;
            const int h = nt * 16 + colx;
            unsigned int w[4];
            #pragma unroll
            for (int jj = 0; jj < 4; ++jj) {
                const int f0 = k * 32 + qd * 8 + jj * 2;
                const int f1 = f0 + 1;
                const unsigned int lo = (f0 < NF && h < NH) ? f2bf(Ws[f0 * NH + h]) : 0;
                const unsigned int hi = (f1 < NF && h < NH) ? f2bf(Ws[f1 * NH + h]) : 0;
                w[jj] = lo | (hi << 16);
            }
            ((u32x4*)Wb1)[(size_t)ic * 768 + e] = (u32x4){w[0], w[1], w[2], w[3]};
        }
        for (int e = tid; e < 896; e += 512) {
            const int nt = e >> 7, kk = (e >> 6) & 1, ln = e & 63;
            const int colx = ln & 15, qd = ln >> 4;
            const int f = nt * 16 + colx;
            unsigned int w[4];
            #pragma unroll
            for (int jj = 0; jj < 4; ++jj) {
                const int h0 = kk * 32 + qd * 8 + jj * 2;
                const int h1 = h0 + 1;
                const unsigned int lo = (f < NF && h0 < NH) ? f2bf(Ws[f * NH + h0]) : 0;
                const unsigned int hi = (f < NF && h1 < NH) ? f2bf(Ws[f * NH + h1]) : 0;
                w[jj] = lo | (hi << 16);
            }
            ((u32x4*)Wb2)[(size_t)ic * 896 + e] = (u32x4){w[0], w[1], w[2], w[3]};
        }
        __syncthreads();   // protect As/Bs/Ws before next unit overwrites
    }

    // ---- build X A-fragments from LDS: a1[mt][k], M=64, K=128(pad) ----
    bf16x8 a1[4][4];
    #pragma unroll
    for (int mt = 0; mt < 4; ++mt) {
        const float* xr = xs + (mt * 16 + col) * XPAD;
        #pragma unroll
        for (int k = 0; k < 4; ++k) {
            if (k < 3 || quad == 0)
                a1[mt][k] = pack8(*(const float4*)(xr + k * 32 + quad * 8),
                                  *(const float4*)(xr + k * 32 + quad * 8 + 4));
            else
                a1[mt][k] = __builtin_bit_cast(bf16x8, (u32x4){0, 0, 0, 0});
        }
    }

    // ---- grid-wide: all Wb writes visible to all XCDs, then sync ----
    __threadfence();
    cooperative_groups::this_grid().sync();

    const u32x4* wb1i = (const u32x4*)Wb1 + (size_t)i * NC * 768;
    const u32x4* wb2i = (const u32x4*)Wb2 + (size_t)i * NC * 896;

    // ---- issue pass1 first B-frag load (c = wav) ----
    u32x4 bufA[12];
    {
        const u32x4* p = wb1i + (size_t)wav * 768;
        #pragma unroll
        for (int e = 0; e < 12; ++e) bufA[e] = p[e * 64 + lane];
    }

    // ---- pass 1: H[mt][nt] accumulators (M=64, N=48); wave's c = wav+8k ----
    f32x4 H[4][3];
    #pragma unroll
    for (int mt = 0; mt < 4; ++mt)
        #pragma unroll
        for (int nt = 0; nt < 3; ++nt)
            H[mt][nt] = (f32x4){0.f, 0.f, 0.f, 0.f};

    #pragma unroll 1
    for (int cc = 0; cc < NC / 8; ++cc) {
        const int c = wav + cc * 8;
        #pragma unroll
        for (int nt = 0; nt < 3; ++nt) {
            #pragma unroll
            for (int mt = 0; mt < 4; ++mt) {
                f32x4 P = (f32x4){0.f, 0.f, 0.f, 0.f};
                #pragma unroll
                for (int k = 0; k < 4; ++k)
                    P = __builtin_amdgcn_mfma_f32_16x16x32_bf16(
                        a1[mt][k], __builtin_bit_cast(bf16x8, bufA[nt * 4 + k]), P, 0, 0, 0);
                const float4 mv = *(const float4*)&msxT[c * MSTR + mt * 16 + quad * 4];
                H[mt][nt][0] += mv.x * P[0];
                H[mt][nt][1] += mv.y * P[1];
                H[mt][nt][2] += mv.z * P[2];
                H[mt][nt][3] += mv.w * P[3];
            }
            // nt-group fully consumed -> reload same slots with next c's frags
            if (cc < NC / 8 - 1) {
                const u32x4* p = wb1i + (size_t)(c + 8) * 768;
                #pragma unroll
                for (int k = 0; k < 4; ++k)
                    bufA[nt * 4 + k] = p[(nt * 4 + k) * 64 + lane];
            }
        }
    }

    // ---- pass2 ownership: fh = nt-range (0:nt0-3, 1:nt4-6), cp = c-phase ----
    const int fh  = wav >> 2;        // 0,1
    const int cp  = wav & 3;         // 0..3; wave's c = cp + 4*cc (10 c's)
    const int ne  = fh ? 3 : 4;      // nt tiles this wave
    const int nb  = fh * 4;          // nt base

    // ---- issue pass2 first B-frag load (c = cp) before LDS phases ----
    u32x4 buf2A[8];
    {
        const u32x4* p = wb2i + (size_t)cp * 896;
        #pragma unroll
        for (int j = 0; j < 4; ++j) {
            #pragma unroll
            for (int kk = 0; kk < 2; ++kk) {
                buf2A[j * 2 + kk] = (u32x4){0, 0, 0, 0};
                if (j < ne)
                    buf2A[j * 2 + kk] = p[((nb + j) * 2 + kk) * 64 + lane];
            }
        }
    }

    // ---- write per-wave H partials (bf16): hsP[wav][b][h] ----
    #pragma unroll
    for (int mt = 0; mt < 4; ++mt)
        #pragma unroll
        for (int nt = 0; nt < 3; ++nt)
            #pragma unroll
            for (int r = 0; r < 4; ++r) {
                const int b = mt * 16 + quad * 4 + r;
                const int h = nt * 16 + col;
                region[(wav * 64 + b) * 48 + h] = f2bf(H[mt][nt][r]);
            }
    __syncthreads();

    // ---- 8-way reduce into slot 0; zero the h=40..47 pad columns ----
    for (int idx = tid; idx < BT * 48; idx += 512) {
        const int b = idx / 48, h = idx % 48;
        float s = 0.f;
        #pragma unroll
        for (int g = 0; g < 8; ++g) s += bf2f(region[(g * 64 + b) * 48 + h]);
        region[b * 48 + h] = (h < NH) ? f2bf(s) : (unsigned short)0;
    }
    __syncthreads();

    // ---- pass2 A-frags for ALL 4 mt (K=40 pad 64) ----
    bf16x8 a2[4][2];
    #pragma unroll
    for (int mt = 0; mt < 4; ++mt) {
        const int b = mt * 16 + col;
        #pragma unroll
        for (int kk = 0; kk < 2; ++kk)
            a2[mt][kk] = *(const bf16x8*)&region[b * 48 + kk * 32 + quad * 8];
    }
    __syncthreads();  // everyone done reading hsP before outP overwrites region

    // ---- pass 2: Ot[mt][j]; 10 c's per wave, depth-1 in-place reload ----
    f32x4 Ot[4][4];
    #pragma unroll
    for (int mt = 0; mt < 4; ++mt)
        #pragma unroll
        for (int j = 0; j < 4; ++j)
            Ot[mt][j] = (f32x4){0.f, 0.f, 0.f, 0.f};

    #pragma unroll 1
    for (int cc = 0; cc < NC / 4; ++cc) {
        const int c = cp + cc * 4;
        #pragma unroll
        for (int j = 0; j < 4; ++j) {
            if (j < ne) {
                #pragma unroll
                for (int mt = 0; mt < 4; ++mt) {
                    f32x4 P = (f32x4){0.f, 0.f, 0.f, 0.f};
                    P = __builtin_amdgcn_mfma_f32_16x16x32_bf16(
                        a2[mt][0], __builtin_bit_cast(bf16x8, buf2A[j * 2 + 0]), P, 0, 0, 0);
                    P = __builtin_amdgcn_mfma_f32_16x16x32_bf16(
                        a2[mt][1], __builtin_bit_cast(bf16x8, buf2A[j * 2 + 1]), P, 0, 0, 0);
                    const float4 mv = *(const float4*)&msxT[c * MSTR + mt * 16 + quad * 4];
                    Ot[mt][j][0] += mv.x * P[0];
                    Ot[mt][j][1] += mv.y * P[1];
                    Ot[mt][j][2] += mv.z * P[2];
                    Ot[mt][j][3] += mv.w * P[3];
                }
                // j-group consumed -> reload same slots with next c's frags
                if (cc < NC / 4 - 1) {
                    const u32x4* p = wb2i + (size_t)(c + 4) * 896;
                    #pragma unroll
                    for (int kk = 0; kk < 2; ++kk)
                        buf2A[j * 2 + kk] = p[((nb + j) * 2 + kk) * 64 + lane];
                }
            }
        }
    }

    // ---- write out partials (bf16): outP[cp][b][f] ----
    #pragma unroll
    for (int mt = 0; mt < 4; ++mt)
        #pragma unroll
        for (int j = 0; j < 4; ++j) {
            if (j < ne) {
                const int f = (nb + j) * 16 + col;
                if (f < NF) {
                    #pragma unroll
                    for (int r = 0; r < 4; ++r) {
                        const int b = mt * 16 + quad * 4 + r;
                        region[(cp * 64 + b) * 112 + f] = f2bf(Ot[mt][j][r]);
                    }
                }
            }
        }
    __syncthreads();

    // ---- final: 4-way reduce over cp + bias + relu, coalesced store ----
    for (int idx = tid; idx < BT * NF; idx += 512) {
        const int b = idx / NF, f = idx % NF;
        float s = 0.f;
        #pragma unroll
        for (int p = 0; p < 4; ++p)
            s += bf2f(region[(p * 64 + b) * 112 + f]);
        const float v = s + b_final[i * NF + f];
        out[((size_t)(b0 + b) * NI + i) * NF + f] = fmaxf(v, 0.f);
    }
}

extern "C" void kernel_launch(void* const* d_in, const int* in_sizes, int n_in,
                              void* d_out, int out_size, void* d_ws, size_t ws_size,
                              hipStream_t stream) {
    const float* x       = (const float*)d_in[0];  // (2048, 8, 100)
    const float* tk_mask = (const float*)d_in[1];  // (2048, 8, 40)
    const float* A       = (const float*)d_in[2];  // (8, 40, 100, 41)
    const float* Bp      = (const float*)d_in[3];  // (8, 40, 41, 40)
    const float* b_final = (const float*)d_in[4];  // (8, 100)
    float* out = (float*)d_out;                    // (2048, 8, 100)

    unsigned short* Wb1 = (unsigned short*)d_ws;
    unsigned short* Wb2 = Wb1 + (size_t)NI * NC * 768 * 8;

    void* args[] = {(void*)&x, (void*)&tk_mask, (void*)&A, (void*)&Bp,
                    (void*)&b_final, (void*)&Wb1, (void*)&Wb2, (void*)&out};
    hipLaunchCooperativeKernel((void*)merged_kernel, dim3((BSZ / BT) * NI),
                               dim3(512), args, 0, stream);
}

// Round 14
// 104.990 us; speedup vs baseline: 1.8216x; 1.8216x over previous
//
#include <hip/hip_runtime.h>

#define NI 8
#define NF 100
#define NH 40
#define NC 40
#define NM 41
#define BSZ 2048
#define BT 64
#define XPAD 104   // x-tile LDS row stride (floats), zero-padded 100..103
#define MSTR 68    // msxT row stride (floats)

typedef __attribute__((ext_vector_type(8))) short bf16x8;
typedef __attribute__((ext_vector_type(4))) float f32x4;
typedef __attribute__((ext_vector_type(4))) unsigned int u32x4;

__device__ __forceinline__ unsigned short f2bf(float f) {
    unsigned int u = __builtin_bit_cast(unsigned int, f);
    u += 0x7fffu + ((u >> 16) & 1u);
    return (unsigned short)(u >> 16);
}
__device__ __forceinline__ float bf2f(unsigned short s) {
    unsigned int u = ((unsigned int)s) << 16;
    return __builtin_bit_cast(float, u);
}
__device__ __forceinline__ bf16x8 pack8(float4 u, float4 v) {
    u32x4 w;
    w.x = (unsigned int)f2bf(u.x) | ((unsigned int)f2bf(u.y) << 16);
    w.y = (unsigned int)f2bf(u.z) | ((unsigned int)f2bf(u.w) << 16);
    w.z = (unsigned int)f2bf(v.x) | ((unsigned int)f2bf(v.y) << 16);
    w.w = (unsigned int)f2bf(v.z) | ((unsigned int)f2bf(v.w) << 16);
    return __builtin_bit_cast(bf16x8, w);
}

// ---------------------------------------------------------------------------
// K1: W_ic = A_ic @ B_ic (fp32), emit bf16 MFMA B-frags (layouts verified R2-R13).
//   Wb1: [ic][nt(3)][k(4)][lane(64)] x16B; n=nt*16+(lane&15), f=k*32+(lane>>4)*8+j
//   Wb2: [ic][nt(7)][kk(2)][lane(64)] x16B; n=nt*16+(lane&15), h=kk*32+(lane>>4)*8+j
// ---------------------------------------------------------------------------
__global__ __launch_bounds__(512) void build_w_kernel(
    const float* __restrict__ A, const float* __restrict__ Bp,
    unsigned short* __restrict__ Wb1, unsigned short* __restrict__ Wb2)
{
    __shared__ __align__(16) float As[NF * NM];
    __shared__ __align__(16) float Bs[NM * NH];
    __shared__ __align__(16) float Ws[NF * NH];
    const int ic = blockIdx.x;
    const float* Ap  = A  + (size_t)ic * NF * NM;
    const float* Bpp = Bp + (size_t)ic * NM * NH;
    for (int idx = threadIdx.x; idx < NF * NM; idx += 512) As[idx] = Ap[idx];
    for (int idx = threadIdx.x; idx < NM * NH; idx += 512) Bs[idx] = Bpp[idx];
    __syncthreads();
    for (int idx = threadIdx.x; idx < NF * (NH / 4); idx += 512) {
        const int f  = idx / (NH / 4);
        const int hq = idx % (NH / 4);
        float4 acc = make_float4(0.f, 0.f, 0.f, 0.f);
        #pragma unroll
        for (int m = 0; m < NM; ++m) {
            const float  a = As[f * NM + m];
            const float4 b = *(const float4*)&Bs[m * NH + hq * 4];
            acc.x += a * b.x; acc.y += a * b.y; acc.z += a * b.z; acc.w += a * b.w;
        }
        *(float4*)&Ws[f * NH + hq * 4] = acc;
    }
    __syncthreads();

    for (int e = threadIdx.x; e < 768; e += 512) {
        const int nt = e >> 8, k = (e >> 6) & 3, ln = e & 63;
        const int colx = ln & 15, quad = ln >> 4;
        const int h = nt * 16 + colx;
        unsigned int w[4];
        #pragma unroll
        for (int jj = 0; jj < 4; ++jj) {
            const int f0 = k * 32 + quad * 8 + jj * 2;
            const int f1 = f0 + 1;
            const unsigned int lo = (f0 < NF && h < NH) ? f2bf(Ws[f0 * NH + h]) : 0;
            const unsigned int hi = (f1 < NF && h < NH) ? f2bf(Ws[f1 * NH + h]) : 0;
            w[jj] = lo | (hi << 16);
        }
        ((u32x4*)Wb1)[(size_t)ic * 768 + e] = (u32x4){w[0], w[1], w[2], w[3]};
    }
    for (int e = threadIdx.x; e < 896; e += 512) {
        const int nt = e >> 7, kk = (e >> 6) & 1, ln = e & 63;
        const int colx = ln & 15, quad = ln >> 4;
        const int f = nt * 16 + colx;
        unsigned int w[4];
        #pragma unroll
        for (int jj = 0; jj < 4; ++jj) {
            const int h0 = kk * 32 + quad * 8 + jj * 2;
            const int h1 = h0 + 1;
            const unsigned int lo = (f < NF && h0 < NH) ? f2bf(Ws[f * NH + h0]) : 0;
            const unsigned int hi = (f < NF && h1 < NH) ? f2bf(Ws[f * NH + h1]) : 0;
            w[jj] = lo | (hi << 16);
        }
        ((u32x4*)Wb2)[(size_t)ic * 896 + e] = (u32x4){w[0], w[1], w[2], w[3]};
    }
}

// ---------------------------------------------------------------------------
// Fused MFMA kernel v8 = R10 (verified best, 105.4us) with both reduce phases
// + epilogue vectorized (b128 LDS group reads, float4 stores). Everything
// else byte-identical to R10; register envelope unchanged (R6/R9/R11/R12
// spill lessons: literal indices only, no extra register buffers).
// ---------------------------------------------------------------------------
__global__ __launch_bounds__(512, 1) void fused_kernel(
    const float* __restrict__ x, const float* __restrict__ mask,
    const float* __restrict__ b_final,
    const unsigned short* __restrict__ Wb1, const unsigned short* __restrict__ Wb2,
    float* __restrict__ out)
{
    __shared__ __align__(16) float msxT[NC * MSTR];          // 10880 B, [c][b]
    __shared__ __align__(16) unsigned char regionB[57344];   // union:
    // phase A: xs[b(64)][XPAD(104)] fp32 (26624 B)
    // phase B: hsP[g(8)][b(64)][h(48)] bf16 (49152 B)
    // phase C: outP[cp(4)][b(64)][f(112)] bf16 (57344 B)
    unsigned short* region = (unsigned short*)regionB;
    float* xs = (float*)regionB;

    const int tid  = threadIdx.x;
    const int lane = tid & 63;
    const int wav  = tid >> 6;       // 0..7
    const int col  = lane & 15;
    const int quad = lane >> 4;
    const int i    = blockIdx.x % NI;
    const int b0   = (blockIdx.x / NI) * BT;

    const u32x4* wb1i = (const u32x4*)Wb1 + (size_t)i * NC * 768;
    const u32x4* wb2i = (const u32x4*)Wb2 + (size_t)i * NC * 896;

    // ---- issue pass1 first B-frag load (c = wav) before anything else ----
    u32x4 bufA[12];
    {
        const u32x4* p = wb1i + (size_t)wav * 768;
        #pragma unroll
        for (int e = 0; e < 12; ++e) bufA[e] = p[e * 64 + lane];
    }

    // ---- stage mask (fp32, transposed) + x tile (coalesced float4) ----
    for (int idx = tid; idx < BT * NC; idx += 512) {
        const int b = idx / NC, c = idx % NC;     // coalesced global read
        msxT[c * MSTR + b] = mask[((size_t)(b0 + b) * NI + i) * NC + c];
    }
    for (int idx = tid; idx < BT * (XPAD / 4); idx += 512) {
        const int row = idx / (XPAD / 4), fq = idx % (XPAD / 4);
        float4 v = make_float4(0.f, 0.f, 0.f, 0.f);
        if (fq < NF / 4)
            v = *(const float4*)(x + ((size_t)(b0 + row) * NI + i) * NF + fq * 4);
        *(float4*)&xs[row * XPAD + fq * 4] = v;
    }
    __syncthreads();

    // ---- build X A-fragments from LDS: a1[mt][k], M=64, K=128(pad) ----
    bf16x8 a1[4][4];
    #pragma unroll
    for (int mt = 0; mt < 4; ++mt) {
        const float* xr = xs + (mt * 16 + col) * XPAD;
        #pragma unroll
        for (int k = 0; k < 4; ++k) {
            if (k < 3 || quad == 0)
                a1[mt][k] = pack8(*(const float4*)(xr + k * 32 + quad * 8),
                                  *(const float4*)(xr + k * 32 + quad * 8 + 4));
            else
                a1[mt][k] = __builtin_bit_cast(bf16x8, (u32x4){0, 0, 0, 0});
        }
    }
    __syncthreads();  // all waves done reading xs before hsP overwrites region

    // ---- pass 1: H[mt][nt] accumulators (M=64, N=48); wave's c = wav+8k ----
    f32x4 H[4][3];
    #pragma unroll
    for (int mt = 0; mt < 4; ++mt)
        #pragma unroll
        for (int nt = 0; nt < 3; ++nt)
            H[mt][nt] = (f32x4){0.f, 0.f, 0.f, 0.f};

    #pragma unroll 1
    for (int cc = 0; cc < NC / 8; ++cc) {
        const int c = wav + cc * 8;
        #pragma unroll
        for (int nt = 0; nt < 3; ++nt) {
            #pragma unroll
            for (int mt = 0; mt < 4; ++mt) {
                f32x4 P = (f32x4){0.f, 0.f, 0.f, 0.f};
                #pragma unroll
                for (int k = 0; k < 4; ++k)
                    P = __builtin_amdgcn_mfma_f32_16x16x32_bf16(
                        a1[mt][k], __builtin_bit_cast(bf16x8, bufA[nt * 4 + k]), P, 0, 0, 0);
                const float4 mv = *(const float4*)&msxT[c * MSTR + mt * 16 + quad * 4];
                H[mt][nt][0] += mv.x * P[0];
                H[mt][nt][1] += mv.y * P[1];
                H[mt][nt][2] += mv.z * P[2];
                H[mt][nt][3] += mv.w * P[3];
            }
            // nt-group fully consumed -> reload same slots with next c's frags
            if (cc < NC / 8 - 1) {
                const u32x4* p = wb1i + (size_t)(c + 8) * 768;
                #pragma unroll
                for (int k = 0; k < 4; ++k)
                    bufA[nt * 4 + k] = p[(nt * 4 + k) * 64 + lane];
            }
        }
    }

    // ---- pass2 ownership: fh = nt-range (0:nt0-3, 1:nt4-6), cp = c-phase ----
    const int fh  = wav >> 2;        // 0,1
    const int cp  = wav & 3;         // 0..3; wave's c = cp + 4*cc (10 c's)
    const int ne  = fh ? 3 : 4;      // nt tiles this wave
    const int nb  = fh * 4;          // nt base

    // ---- issue pass2 first B-frag load (c = cp) before LDS phases ----
    u32x4 buf2A[8];
    {
        const u32x4* p = wb2i + (size_t)cp * 896;
        #pragma unroll
        for (int j = 0; j < 4; ++j) {
            #pragma unroll
            for (int kk = 0; kk < 2; ++kk) {
                buf2A[j * 2 + kk] = (u32x4){0, 0, 0, 0};
                if (j < ne)
                    buf2A[j * 2 + kk] = p[((nb + j) * 2 + kk) * 64 + lane];
            }
        }
    }

    // ---- write per-wave H partials (bf16): hsP[wav][b][h] ----
    #pragma unroll
    for (int mt = 0; mt < 4; ++mt)
        #pragma unroll
        for (int nt = 0; nt < 3; ++nt)
            #pragma unroll
            for (int r = 0; r < 4; ++r) {
                const int b = mt * 16 + quad * 4 + r;
                const int h = nt * 16 + col;
                region[(wav * 64 + b) * 48 + h] = f2bf(H[mt][nt][r]);
            }
    __syncthreads();

    // ---- 8-way reduce into slot 0, VECTORIZED: thread = (b, 8-h group) ----
    // 64 b x 6 groups = 384 items; 8x ds_read_b128 each, conflict-free.
    for (int idx = tid; idx < BT * 6; idx += 512) {
        const int b = idx / 6, hq = idx % 6;
        if (hq == 5) {   // h=40..47 pad columns -> zero
            *(u32x4*)&region[b * 48 + 40] = (u32x4){0, 0, 0, 0};
        } else {
            float s[8] = {0.f, 0.f, 0.f, 0.f, 0.f, 0.f, 0.f, 0.f};
            #pragma unroll
            for (int g = 0; g < 8; ++g) {
                const u32x4 v = *(const u32x4*)&region[(g * 64 + b) * 48 + hq * 8];
                const unsigned int vv[4] = {v.x, v.y, v.z, v.w};
                #pragma unroll
                for (int q = 0; q < 4; ++q) {
                    s[q * 2 + 0] += bf2f((unsigned short)(vv[q] & 0xffffu));
                    s[q * 2 + 1] += bf2f((unsigned short)(vv[q] >> 16));
                }
            }
            u32x4 o;
            o.x = (unsigned int)f2bf(s[0]) | ((unsigned int)f2bf(s[1]) << 16);
            o.y = (unsigned int)f2bf(s[2]) | ((unsigned int)f2bf(s[3]) << 16);
            o.z = (unsigned int)f2bf(s[4]) | ((unsigned int)f2bf(s[5]) << 16);
            o.w = (unsigned int)f2bf(s[6]) | ((unsigned int)f2bf(s[7]) << 16);
            *(u32x4*)&region[b * 48 + hq * 8] = o;
        }
    }
    __syncthreads();

    // ---- pass2 A-frags for ALL 4 mt (K=40 pad 64) ----
    bf16x8 a2[4][2];
    #pragma unroll
    for (int mt = 0; mt < 4; ++mt) {
        const int b = mt * 16 + col;
        #pragma unroll
        for (int kk = 0; kk < 2; ++kk)
            a2[mt][kk] = *(const bf16x8*)&region[b * 48 + kk * 32 + quad * 8];
    }
    __syncthreads();  // everyone done reading hsP before outP overwrites region

    // ---- pass 2: Ot[mt][j]; 10 c's per wave, depth-1 in-place reload ----
    f32x4 Ot[4][4];
    #pragma unroll
    for (int mt = 0; mt < 4; ++mt)
        #pragma unroll
        for (int j = 0; j < 4; ++j)
            Ot[mt][j] = (f32x4){0.f, 0.f, 0.f, 0.f};

    #pragma unroll 1
    for (int cc = 0; cc < NC / 4; ++cc) {
        const int c = cp + cc * 4;
        #pragma unroll
        for (int j = 0; j < 4; ++j) {
            if (j < ne) {
                #pragma unroll
                for (int mt = 0; mt < 4; ++mt) {
                    f32x4 P = (f32x4){0.f, 0.f, 0.f, 0.f};
                    P = __builtin_amdgcn_mfma_f32_16x16x32_bf16(
                        a2[mt][0], __builtin_bit_cast(bf16x8, buf2A[j * 2 + 0]), P, 0, 0, 0);
                    P = __builtin_amdgcn_mfma_f32_16x16x32_bf16(
                        a2[mt][1], __builtin_bit_cast(bf16x8, buf2A[j * 2 + 1]), P, 0, 0, 0);
                    const float4 mv = *(const float4*)&msxT[c * MSTR + mt * 16 + quad * 4];
                    Ot[mt][j][0] += mv.x * P[0];
                    Ot[mt][j][1] += mv.y * P[1];
                    Ot[mt][j][2] += mv.z * P[2];
                    Ot[mt][j][3] += mv.w * P[3];
                }
                // j-group consumed -> reload same slots with next c's frags
                if (cc < NC / 4 - 1) {
                    const u32x4* p = wb2i + (size_t)(c + 4) * 896;
                    #pragma unroll
                    for (int kk = 0; kk < 2; ++kk)
                        buf2A[j * 2 + kk] = p[((nb + j) * 2 + kk) * 64 + lane];
                }
            }
        }
    }

    // ---- write out partials (bf16): outP[cp][b][f] ----
    #pragma unroll
    for (int mt = 0; mt < 4; ++mt)
        #pragma unroll
        for (int j = 0; j < 4; ++j) {
            if (j < ne) {
                const int f = (nb + j) * 16 + col;
                if (f < NF) {
                    #pragma unroll
                    for (int r = 0; r < 4; ++r) {
                        const int b = mt * 16 + quad * 4 + r;
                        region[(cp * 64 + b) * 112 + f] = f2bf(Ot[mt][j][r]);
                    }
                }
            }
        }
    __syncthreads();

    // ---- final reduce + bias + relu, VECTORIZED: thread = (b, 8-f group) ----
    // 64 b x 13 groups (f 0..103; store masks f<100). 4x b128 reads each.
    for (int idx = tid; idx < BT * 13; idx += 512) {
        const int b = idx / 13, fg = idx % 13;
        const int f0 = fg * 8;
        float s[8] = {0.f, 0.f, 0.f, 0.f, 0.f, 0.f, 0.f, 0.f};
        #pragma unroll
        for (int p = 0; p < 4; ++p) {
            const u32x4 v = *(const u32x4*)&region[(p * 64 + b) * 112 + f0];
            const unsigned int vv[4] = {v.x, v.y, v.z, v.w};
            #pragma unroll
            for (int q = 0; q < 4; ++q) {
                s[q * 2 + 0] += bf2f((unsigned short)(vv[q] & 0xffffu));
                s[q * 2 + 1] += bf2f((unsigned short)(vv[q] >> 16));
            }
        }
        const float* bfp = b_final + i * NF + f0;
        float* op = out + ((size_t)(b0 + b) * NI + i) * NF + f0;
        const float4 bias0 = *(const float4*)bfp;   // f0..f0+3 (<=99 always)
        float4 o0;
        o0.x = fmaxf(s[0] + bias0.x, 0.f);
        o0.y = fmaxf(s[1] + bias0.y, 0.f);
        o0.z = fmaxf(s[2] + bias0.z, 0.f);
        o0.w = fmaxf(s[3] + bias0.w, 0.f);
        *(float4*)op = o0;
        if (fg < 12) {                              // f0+4..f0+7 < 100
            const float4 bias1 = *(const float4*)(bfp + 4);
            float4 o1;
            o1.x = fmaxf(s[4] + bias1.x, 0.f);
            o1.y = fmaxf(s[5] + bias1.y, 0.f);
            o1.z = fmaxf(s[6] + bias1.z, 0.f);
            o1.w = fmaxf(s[7] + bias1.w, 0.f);
            *(float4*)(op + 4) = o1;
        }
    }
}

extern "C" void kernel_launch(void* const* d_in, const int* in_sizes, int n_in,
                              void* d_out, int out_size, void* d_ws, size_t ws_size,
                              hipStream_t stream) {
    const float* x       = (const float*)d_in[0];  // (2048, 8, 100)
    const float* tk_mask = (const float*)d_in[1];  // (2048, 8, 40)
    const float* A       = (const float*)d_in[2];  // (8, 40, 100, 41)
    const float* Bp      = (const float*)d_in[3];  // (8, 40, 41, 40)
    const float* b_final = (const float*)d_in[4];  // (8, 100)
    float* out = (float*)d_out;                    // (2048, 8, 100)

    unsigned short* Wb1 = (unsigned short*)d_ws;
    unsigned short* Wb2 = Wb1 + (size_t)NI * NC * 768 * 8;

    build_w_kernel<<<NI * NC, 512, 0, stream>>>(A, Bp, Wb1, Wb2);
    fused_kernel<<<(BSZ / BT) * NI, 512, 0, stream>>>(x, tk_mask, b_final, Wb1, Wb2, out);
}